// Round 1
// baseline (296.418 us; speedup 1.0000x reference)
//
#include <hip/hip_runtime.h>
#include <hip/hip_bf16.h>
#include <stdint.h>

#define S_LEN 2304
#define C_DIM 512
#define NH 8
#define HD 64

typedef __attribute__((ext_vector_type(8))) __bf16 bf16x8;
typedef __attribute__((ext_vector_type(4))) float f32x4;
typedef __attribute__((ext_vector_type(8))) unsigned short u16x8;

__device__ __forceinline__ unsigned short bf16u(float f) {
  __hip_bfloat16 h = __float2bfloat16(f);
  return __builtin_bit_cast(unsigned short, h);
}

__device__ __forceinline__ void load_lds16(void* g, void* l) {
  __builtin_amdgcn_global_load_lds(
      (__attribute__((address_space(1))) void*)g,
      (__attribute__((address_space(3))) void*)l, 16, 0, 0);
}

// ---------------- GroupNorm stats: one block per (b, group) ----------------
__global__ __launch_bounds__(256) void gn_stats_kernel(const float* __restrict__ x,
                                                       float* __restrict__ stats) {
  const int bg = blockIdx.x;  // b*32 + g ; group data is one contiguous 36864-float run
  const float4* src = (const float4*)(x + (size_t)bg * 36864);
  float s = 0.f, s2 = 0.f;
#pragma unroll
  for (int i = 0; i < 36; ++i) {
    float4 v = src[i * 256 + threadIdx.x];
    s += v.x + v.y + v.z + v.w;
    s2 += v.x * v.x + v.y * v.y + v.z * v.z + v.w * v.w;
  }
#pragma unroll
  for (int off = 1; off < 64; off <<= 1) {
    s += __shfl_xor(s, off);
    s2 += __shfl_xor(s2, off);
  }
  __shared__ float red[8];
  const int wid = threadIdx.x >> 6;
  if ((threadIdx.x & 63) == 0) { red[wid] = s; red[wid + 4] = s2; }
  __syncthreads();
  if (threadIdx.x == 0) {
    float S = red[0] + red[1] + red[2] + red[3];
    float S2 = red[4] + red[5] + red[6] + red[7];
    float mu = S * (1.f / 36864.f);
    float var = S2 * (1.f / 36864.f) - mu * mu;
    stats[bg * 2] = mu;
    stats[bg * 2 + 1] = rsqrtf(var + 1e-5f);
  }
}

// ------- GN normalize + transpose (b,c,s)->(b,s,c), fp32 -> bf16 ----------
__global__ __launch_bounds__(256) void gn_norm_t_kernel(
    const float* __restrict__ x, const float* __restrict__ gamma,
    const float* __restrict__ beta, const float* __restrict__ stats,
    unsigned short* __restrict__ xn) {
  __shared__ float tile[64][68];
  const int s0 = blockIdx.x * 64, c0 = blockIdx.y * 64, b = blockIdx.z;
  const int tid = threadIdx.x;
  {
    const int cl = tid >> 2, sc = (tid & 3) * 16;
    const float* src = x + ((size_t)b * C_DIM + c0 + cl) * S_LEN + s0 + sc;
#pragma unroll
    for (int i = 0; i < 4; ++i)
      *(float4*)&tile[cl][sc + i * 4] = *(const float4*)(src + i * 4);
  }
  __syncthreads();
  const int sl = tid >> 2, cc = (tid & 3) * 16;
  const int g = (c0 + cc) >> 4;  // 16 channels per group, chunk spans exactly one group
  const float mu = stats[((size_t)b * 32 + g) * 2];
  const float rs = stats[((size_t)b * 32 + g) * 2 + 1];
  u16x8 o0, o1;
#pragma unroll
  for (int j = 0; j < 8; ++j) {
    const int c = c0 + cc + j;
    o0[j] = bf16u((tile[cc + j][sl] - mu) * rs * gamma[c] + beta[c]);
  }
#pragma unroll
  for (int j = 0; j < 8; ++j) {
    const int c = c0 + cc + 8 + j;
    o1[j] = bf16u((tile[cc + 8 + j][sl] - mu) * rs * gamma[c] + beta[c]);
  }
  unsigned short* dst = xn + ((size_t)b * S_LEN + s0 + sl) * C_DIM + c0 + cc;
  *(u16x8*)dst = o0;
  *(u16x8*)(dst + 8) = o1;
}

// --------- weight transpose: w (K,N) fp32 -> wT (N,K) bf16 -----------------
__global__ __launch_bounds__(256) void wt_kernel(const float* __restrict__ w,
                                                 unsigned short* __restrict__ wT,
                                                 int N, int K) {
  __shared__ float tile[64][68];
  const int n0 = blockIdx.x * 64, k0 = blockIdx.y * 64;
  const int tid = threadIdx.x;
  {
    const int kl = tid >> 2, nc = (tid & 3) * 16;
    const float* src = w + (size_t)(k0 + kl) * N + n0 + nc;
#pragma unroll
    for (int i = 0; i < 4; ++i)
      *(float4*)&tile[kl][nc + i * 4] = *(const float4*)(src + i * 4);
  }
  __syncthreads();
  const int nl = tid >> 2, kc = (tid & 3) * 16;
  u16x8 o0, o1;
#pragma unroll
  for (int j = 0; j < 8; ++j) o0[j] = bf16u(tile[kc + j][nl]);
#pragma unroll
  for (int j = 0; j < 8; ++j) o1[j] = bf16u(tile[kc + 8 + j][nl]);
  unsigned short* dst = wT + (size_t)(n0 + nl) * K + k0 + kc;
  *(u16x8*)dst = o0;
  *(u16x8*)(dst + 8) = o1;
}

// ------------- shared 128x128 GEMM mainloop (A:(M,K) B:(N,K), bf16) --------
__device__ __forceinline__ void gemm128_core(const unsigned short* __restrict__ A,
                                             const unsigned short* __restrict__ B,
                                             int K, int m0, int n0, short* lds_a,
                                             short* lds_b, f32x4 (&acc)[4][4]) {
  const int tid = threadIdx.x;
  const int lane = tid & 63, wid = tid >> 6;
  const int wr = wid >> 1, wc = wid & 1;
  const f32x4 fzero = {0.f, 0.f, 0.f, 0.f};
#pragma unroll
  for (int i = 0; i < 4; ++i)
#pragma unroll
    for (int j = 0; j < 4; ++j) acc[i][j] = fzero;
  const int lrow = lane >> 3;       // 0..7
  const int lcol = (lane & 7) * 8;  // bf16 elems; *2 = 16B chunks
  for (int kt = 0; kt < K; kt += 64) {
#pragma unroll
    for (int i = 0; i < 4; ++i) {
      const int r0 = (wid * 4 + i) * 8;
      load_lds16((void*)(A + (size_t)(m0 + r0 + lrow) * K + kt + lcol), lds_a + r0 * 64);
      load_lds16((void*)(B + (size_t)(n0 + r0 + lrow) * K + kt + lcol), lds_b + r0 * 64);
    }
    __syncthreads();
#pragma unroll
    for (int ks = 0; ks < 2; ++ks) {
      bf16x8 af[4], bfr[4];
#pragma unroll
      for (int mf = 0; mf < 4; ++mf)
        af[mf] = *(const bf16x8*)(lds_a + ((wr * 64 + mf * 16 + (lane & 15)) * 64 +
                                           ks * 32 + (lane >> 4) * 8));
#pragma unroll
      for (int nf = 0; nf < 4; ++nf)
        bfr[nf] = *(const bf16x8*)(lds_b + ((wc * 64 + nf * 16 + (lane & 15)) * 64 +
                                            ks * 32 + (lane >> 4) * 8));
#pragma unroll
      for (int mf = 0; mf < 4; ++mf)
#pragma unroll
        for (int nf = 0; nf < 4; ++nf)
          acc[mf][nf] =
              __builtin_amdgcn_mfma_f32_16x16x32_bf16(af[mf], bfr[nf], acc[mf][nf], 0, 0, 0);
    }
    __syncthreads();
  }
}

// --------------- QKV GEMM: C[s, 3c] scattered to Q/K/V (bh,s,64) -----------
__global__ __launch_bounds__(256) void qkv_gemm_kernel(
    const unsigned short* __restrict__ xn, const unsigned short* __restrict__ wT,
    const float* __restrict__ bq, unsigned short* __restrict__ Q,
    unsigned short* __restrict__ Kb, unsigned short* __restrict__ V) {
  __shared__ short lds_a[128 * 64];
  __shared__ short lds_b[128 * 64];
  const int b = blockIdx.z;
  const int m0 = blockIdx.x * 128, n0 = blockIdx.y * 128;
  f32x4 acc[4][4];
  gemm128_core(xn + (size_t)b * S_LEN * C_DIM, wT, C_DIM, m0, n0, lds_a, lds_b, acc);
  const int lane = threadIdx.x & 63, wid = threadIdx.x >> 6;
  const int wr = wid >> 1, wc = wid & 1;
#pragma unroll
  for (int mf = 0; mf < 4; ++mf) {
#pragma unroll
    for (int nf = 0; nf < 4; ++nf) {
      const int n = n0 + wc * 64 + nf * 16 + (lane & 15);
      const int part = n >> 9;
      const int h = (n >> 6) & 7;
      const int d = n & 63;
      unsigned short* dst = part == 0 ? Q : (part == 1 ? Kb : V);
      const float bias = bq[n];
#pragma unroll
      for (int r = 0; r < 4; ++r) {
        const int m = m0 + wr * 64 + mf * 16 + (lane >> 4) * 4 + r;
        dst[((size_t)(b * NH + h) * S_LEN + m) * HD + d] = bf16u(acc[mf][nf][r] + bias);
      }
    }
  }
}

// ----------------------------- flash attention -----------------------------
__global__ __launch_bounds__(256) void attn_kernel(const unsigned short* __restrict__ Q,
                                                   const unsigned short* __restrict__ K,
                                                   const unsigned short* __restrict__ V,
                                                   unsigned short* __restrict__ O) {
  __shared__ unsigned short lds_k[64 * 72];
  __shared__ unsigned short lds_vt[64 * 72];
  __shared__ unsigned short lds_p[4][16 * 72];
  const int tid = threadIdx.x, lane = tid & 63, wid = tid >> 6;
  const int bh = blockIdx.y, b = bh >> 3, h = bh & 7;
  const int q0 = blockIdx.x * 64;
  const size_t base = (size_t)bh * S_LEN * HD;
  bf16x8 qf[2];
  {
    const int qrow = q0 + wid * 16 + (lane & 15);
#pragma unroll
    for (int ks = 0; ks < 2; ++ks)
      qf[ks] = *(const bf16x8*)(Q + base + (size_t)qrow * HD + ks * 32 + (lane >> 4) * 8);
  }
  const f32x4 fzero = {0.f, 0.f, 0.f, 0.f};
  f32x4 oacc[4];
  float mrow[4], lrow[4];
#pragma unroll
  for (int i = 0; i < 4; ++i) { oacc[i] = fzero; mrow[i] = -1e30f; lrow[i] = 0.f; }
  const int r_st = tid >> 3;       // 0..31
  const int c8 = (tid & 7) * 8;    // column chunk (bf16 elems)
  for (int kt = 0; kt < 36; ++kt) {
    {  // stage K tile (row-major, pitch 72) and V^T tile (d-major, pitch 72)
      const unsigned short* kp = K + base + (size_t)(kt * 64 + r_st) * HD + c8;
      *(u16x8*)&lds_k[r_st * 72 + c8] = *(const u16x8*)kp;
      *(u16x8*)&lds_k[(r_st + 32) * 72 + c8] = *(const u16x8*)(kp + 32 * HD);
      const unsigned short* vp = V + base + (size_t)(kt * 64 + r_st) * HD + c8;
      u16x8 v0 = *(const u16x8*)vp;
      u16x8 v1 = *(const u16x8*)(vp + 32 * HD);
#pragma unroll
      for (int j = 0; j < 8; ++j) {
        lds_vt[(c8 + j) * 72 + r_st] = v0[j];
        lds_vt[(c8 + j) * 72 + r_st + 32] = v1[j];
      }
    }
    __syncthreads();
    // S = Q K^T
    f32x4 sacc[4];
#pragma unroll
    for (int nf = 0; nf < 4; ++nf) sacc[nf] = fzero;
#pragma unroll
    for (int nf = 0; nf < 4; ++nf) {
#pragma unroll
      for (int ks = 0; ks < 2; ++ks) {
        bf16x8 kf = *(const bf16x8*)&lds_k[(nf * 16 + (lane & 15)) * 72 + ks * 32 +
                                           (lane >> 4) * 8];
        sacc[nf] = __builtin_amdgcn_mfma_f32_16x16x32_bf16(qf[ks], kf, sacc[nf], 0, 0, 0);
      }
    }
#pragma unroll
    for (int nf = 0; nf < 4; ++nf)
#pragma unroll
      for (int r = 0; r < 4; ++r) sacc[nf][r] *= 0.125f;
    // online softmax (rows r = (lane>>4)*4 + reg, reduce across 16-lane groups)
    float pmax[4];
#pragma unroll
    for (int r = 0; r < 4; ++r) {
      float m = fmaxf(fmaxf(sacc[0][r], sacc[1][r]), fmaxf(sacc[2][r], sacc[3][r]));
#pragma unroll
      for (int off = 1; off < 16; off <<= 1) m = fmaxf(m, __shfl_xor(m, off));
      pmax[r] = m;
    }
    float corr[4];
#pragma unroll
    for (int r = 0; r < 4; ++r) {
      const float mn = fmaxf(mrow[r], pmax[r]);
      corr[r] = __expf(mrow[r] - mn);
      mrow[r] = mn;
    }
    float rsum[4] = {0.f, 0.f, 0.f, 0.f};
#pragma unroll
    for (int nf = 0; nf < 4; ++nf)
#pragma unroll
      for (int r = 0; r < 4; ++r) {
        const float p = __expf(sacc[nf][r] - mrow[r]);
        sacc[nf][r] = p;
        rsum[r] += p;
      }
#pragma unroll
    for (int r = 0; r < 4; ++r) {
      float rs = rsum[r];
#pragma unroll
      for (int off = 1; off < 16; off <<= 1) rs += __shfl_xor(rs, off);
      lrow[r] = lrow[r] * corr[r] + rs;
#pragma unroll
      for (int nf = 0; nf < 4; ++nf) oacc[nf][r] *= corr[r];
    }
    // P -> per-wave LDS (A-fragment re-layout)
    unsigned short* pl = lds_p[wid];
#pragma unroll
    for (int nf = 0; nf < 4; ++nf)
#pragma unroll
      for (int r = 0; r < 4; ++r)
        pl[((lane >> 4) * 4 + r) * 72 + nf * 16 + (lane & 15)] = bf16u(sacc[nf][r]);
    // O += P V
    bf16x8 pa[2];
#pragma unroll
    for (int ks = 0; ks < 2; ++ks)
      pa[ks] = *(const bf16x8*)&pl[(lane & 15) * 72 + ks * 32 + (lane >> 4) * 8];
#pragma unroll
    for (int nf = 0; nf < 4; ++nf) {
#pragma unroll
      for (int ks = 0; ks < 2; ++ks) {
        bf16x8 vb = *(const bf16x8*)&lds_vt[(nf * 16 + (lane & 15)) * 72 + ks * 32 +
                                            (lane >> 4) * 8];
        oacc[nf] = __builtin_amdgcn_mfma_f32_16x16x32_bf16(pa[ks], vb, oacc[nf], 0, 0, 0);
      }
    }
    __syncthreads();
  }
  float inv[4];
#pragma unroll
  for (int r = 0; r < 4; ++r) inv[r] = 1.f / lrow[r];
#pragma unroll
  for (int nf = 0; nf < 4; ++nf)
#pragma unroll
    for (int r = 0; r < 4; ++r) {
      const int row = (lane >> 4) * 4 + r;
      O[((size_t)b * S_LEN + q0 + wid * 16 + row) * C_DIM + h * HD + nf * 16 + (lane & 15)] =
          bf16u(oacc[nf][r] * inv[r]);
    }
}

// ------------- proj GEMM (M=c_out, N=s) + bias + residual, fp32 out --------
__global__ __launch_bounds__(256) void proj_gemm_kernel(
    const unsigned short* __restrict__ wT, const unsigned short* __restrict__ ao,
    const float* __restrict__ bp, const float* __restrict__ x, float* __restrict__ out) {
  __shared__ short lds_a[128 * 64];
  __shared__ short lds_b[128 * 64];
  const int b = blockIdx.z;
  const int m0 = blockIdx.x * 128, n0 = blockIdx.y * 128;
  f32x4 acc[4][4];
  gemm128_core(wT, ao + (size_t)b * S_LEN * C_DIM, C_DIM, m0, n0, lds_a, lds_b, acc);
  const int lane = threadIdx.x & 63, wid = threadIdx.x >> 6;
  const int wr = wid >> 1, wc = wid & 1;
#pragma unroll
  for (int mf = 0; mf < 4; ++mf) {
#pragma unroll
    for (int nf = 0; nf < 4; ++nf) {
      const int n = n0 + wc * 64 + nf * 16 + (lane & 15);  // s index
#pragma unroll
      for (int r = 0; r < 4; ++r) {
        const int m = m0 + wr * 64 + mf * 16 + (lane >> 4) * 4 + r;  // c index
        const size_t idx = ((size_t)b * C_DIM + m) * S_LEN + n;
        out[idx] = x[idx] + acc[mf][nf][r] + bp[m];
      }
    }
  }
}

extern "C" void kernel_launch(void* const* d_in, const int* in_sizes, int n_in,
                              void* d_out, int out_size, void* d_ws, size_t ws_size,
                              hipStream_t stream) {
  const float* x = (const float*)d_in[0];
  const float* gamma = (const float*)d_in[1];
  const float* beta = (const float*)d_in[2];
  const float* w_qkv = (const float*)d_in[3];
  const float* b_qkv = (const float*)d_in[4];
  const float* w_proj = (const float*)d_in[5];
  const float* b_proj = (const float*)d_in[6];
  float* out = (float*)d_out;

  char* ws = (char*)d_ws;
  float* stats = (float*)ws;                                   // 1 KB
  unsigned short* xn = (unsigned short*)(ws + 1024);           // 9437184 B
  unsigned short* wqkvT = (unsigned short*)(ws + 9438208);     // 1572864 B
  unsigned short* wprojT = (unsigned short*)(ws + 11011072);   // 524288 B
  unsigned short* Qb = (unsigned short*)(ws + 11535360);       // 9437184 B
  unsigned short* Kb = (unsigned short*)(ws + 20972544);       // 9437184 B
  unsigned short* Vb = (unsigned short*)(ws + 30409728);       // 9437184 B
  unsigned short* ao = (unsigned short*)(ws + 39846912);       // 9437184 B -> 49284096 total

  hipLaunchKernelGGL(gn_stats_kernel, dim3(128), dim3(256), 0, stream, x, stats);
  hipLaunchKernelGGL(wt_kernel, dim3(24, 8), dim3(256), 0, stream, w_qkv, wqkvT, 3 * C_DIM, C_DIM);
  hipLaunchKernelGGL(wt_kernel, dim3(8, 8), dim3(256), 0, stream, w_proj, wprojT, C_DIM, C_DIM);
  hipLaunchKernelGGL(gn_norm_t_kernel, dim3(36, 8, 4), dim3(256), 0, stream, x, gamma, beta, stats, xn);
  hipLaunchKernelGGL(qkv_gemm_kernel, dim3(18, 12, 4), dim3(256), 0, stream, xn, wqkvT, b_qkv, Qb, Kb, Vb);
  hipLaunchKernelGGL(attn_kernel, dim3(36, 32), dim3(256), 0, stream, Qb, Kb, Vb, ao);
  hipLaunchKernelGGL(proj_gemm_kernel, dim3(4, 18, 4), dim3(256), 0, stream, wprojT, ao, b_proj, x, out);
}

// Round 2
// 179.309 us; speedup vs baseline: 1.6531x; 1.6531x over previous
//
#include <hip/hip_runtime.h>
#include <hip/hip_bf16.h>
#include <stdint.h>

#define S_LEN 2304
#define C_DIM 512
#define NH 8
#define HD 64

typedef __attribute__((ext_vector_type(8))) __bf16 bf16x8;
typedef __attribute__((ext_vector_type(4))) float f32x4;
typedef __attribute__((ext_vector_type(16))) float f32x16;
typedef __attribute__((ext_vector_type(8))) unsigned short u16x8;
typedef __attribute__((ext_vector_type(4))) unsigned short u16x4;

__device__ __forceinline__ unsigned short bf16u(float f) {
  __hip_bfloat16 h = __float2bfloat16(f);
  return __builtin_bit_cast(unsigned short, h);
}

__device__ __forceinline__ void load_lds16(const void* g, void* l) {
  __builtin_amdgcn_global_load_lds(
      (const __attribute__((address_space(1))) void*)g,
      (__attribute__((address_space(3))) void*)l, 16, 0, 0);
}

// ---------------- GroupNorm stats: one block per (b, group) ----------------
__global__ __launch_bounds__(256) void gn_stats_kernel(const float* __restrict__ x,
                                                       float* __restrict__ stats) {
  const int bg = blockIdx.x;
  const float4* src = (const float4*)(x + (size_t)bg * 36864);
  float s = 0.f, s2 = 0.f;
#pragma unroll
  for (int i = 0; i < 36; ++i) {
    float4 v = src[i * 256 + threadIdx.x];
    s += v.x + v.y + v.z + v.w;
    s2 += v.x * v.x + v.y * v.y + v.z * v.z + v.w * v.w;
  }
#pragma unroll
  for (int off = 1; off < 64; off <<= 1) {
    s += __shfl_xor(s, off);
    s2 += __shfl_xor(s2, off);
  }
  __shared__ float red[8];
  const int wid = threadIdx.x >> 6;
  if ((threadIdx.x & 63) == 0) { red[wid] = s; red[wid + 4] = s2; }
  __syncthreads();
  if (threadIdx.x == 0) {
    float S = red[0] + red[1] + red[2] + red[3];
    float S2 = red[4] + red[5] + red[6] + red[7];
    float mu = S * (1.f / 36864.f);
    float var = S2 * (1.f / 36864.f) - mu * mu;
    stats[bg * 2] = mu;
    stats[bg * 2 + 1] = rsqrtf(var + 1e-5f);
  }
}

// ------- GN normalize + transpose (b,c,s)->(b,s,c), fp32 -> bf16 ----------
__global__ __launch_bounds__(256) void gn_norm_t_kernel(
    const float* __restrict__ x, const float* __restrict__ gamma,
    const float* __restrict__ beta, const float* __restrict__ stats,
    unsigned short* __restrict__ xn) {
  __shared__ float tile[64][68];
  const int s0 = blockIdx.x * 64, c0 = blockIdx.y * 64, b = blockIdx.z;
  const int tid = threadIdx.x;
  {
    const int cl = tid >> 2, sc = (tid & 3) * 16;
    const float* src = x + ((size_t)b * C_DIM + c0 + cl) * S_LEN + s0 + sc;
#pragma unroll
    for (int i = 0; i < 4; ++i)
      *(float4*)&tile[cl][sc + i * 4] = *(const float4*)(src + i * 4);
  }
  __syncthreads();
  const int sl = tid >> 2, cc = (tid & 3) * 16;
  const int g = (c0 + cc) >> 4;
  const float mu = stats[((size_t)b * 32 + g) * 2];
  const float rs = stats[((size_t)b * 32 + g) * 2 + 1];
  u16x8 o0, o1;
#pragma unroll
  for (int j = 0; j < 8; ++j) {
    const int c = c0 + cc + j;
    o0[j] = bf16u((tile[cc + j][sl] - mu) * rs * gamma[c] + beta[c]);
  }
#pragma unroll
  for (int j = 0; j < 8; ++j) {
    const int c = c0 + cc + 8 + j;
    o1[j] = bf16u((tile[cc + 8 + j][sl] - mu) * rs * gamma[c] + beta[c]);
  }
  unsigned short* dst = xn + ((size_t)b * S_LEN + s0 + sl) * C_DIM + c0 + cc;
  *(u16x8*)dst = o0;
  *(u16x8*)(dst + 8) = o1;
}

// --------- weight transpose: w (K,N) fp32 -> wT (N,K) bf16 -----------------
__global__ __launch_bounds__(256) void wt_kernel(const float* __restrict__ w,
                                                 unsigned short* __restrict__ wT,
                                                 int N, int K) {
  __shared__ float tile[64][68];
  const int n0 = blockIdx.x * 64, k0 = blockIdx.y * 64;
  const int tid = threadIdx.x;
  {
    const int kl = tid >> 2, nc = (tid & 3) * 16;
    const float* src = w + (size_t)(k0 + kl) * N + n0 + nc;
#pragma unroll
    for (int i = 0; i < 4; ++i)
      *(float4*)&tile[kl][nc + i * 4] = *(const float4*)(src + i * 4);
  }
  __syncthreads();
  const int nl = tid >> 2, kc = (tid & 3) * 16;
  u16x8 o0, o1;
#pragma unroll
  for (int j = 0; j < 8; ++j) o0[j] = bf16u(tile[kc + j][nl]);
#pragma unroll
  for (int j = 0; j < 8; ++j) o1[j] = bf16u(tile[kc + 8 + j][nl]);
  unsigned short* dst = wT + (size_t)(n0 + nl) * K + k0 + kc;
  *(u16x8*)dst = o0;
  *(u16x8*)(dst + 8) = o1;
}

// ------------- shared 128x128 GEMM mainloop (A:(M,K) B:(N,K), bf16) --------
__device__ __forceinline__ void gemm128_core(const unsigned short* __restrict__ A,
                                             const unsigned short* __restrict__ B,
                                             int K, int m0, int n0, short* lds_a,
                                             short* lds_b, f32x4 (&acc)[4][4]) {
  const int tid = threadIdx.x;
  const int lane = tid & 63, wid = tid >> 6;
  const int wr = wid >> 1, wc = wid & 1;
  const f32x4 fzero = {0.f, 0.f, 0.f, 0.f};
#pragma unroll
  for (int i = 0; i < 4; ++i)
#pragma unroll
    for (int j = 0; j < 4; ++j) acc[i][j] = fzero;
  const int lrow = lane >> 3;
  const int lcol = (lane & 7) * 8;
  for (int kt = 0; kt < K; kt += 64) {
#pragma unroll
    for (int i = 0; i < 4; ++i) {
      const int r0 = (wid * 4 + i) * 8;
      load_lds16((const void*)(A + (size_t)(m0 + r0 + lrow) * K + kt + lcol), lds_a + r0 * 64);
      load_lds16((const void*)(B + (size_t)(n0 + r0 + lrow) * K + kt + lcol), lds_b + r0 * 64);
    }
    __syncthreads();
#pragma unroll
    for (int ks = 0; ks < 2; ++ks) {
      bf16x8 af[4], bfr[4];
#pragma unroll
      for (int mf = 0; mf < 4; ++mf)
        af[mf] = *(const bf16x8*)(lds_a + ((wr * 64 + mf * 16 + (lane & 15)) * 64 +
                                           ks * 32 + (lane >> 4) * 8));
#pragma unroll
      for (int nf = 0; nf < 4; ++nf)
        bfr[nf] = *(const bf16x8*)(lds_b + ((wc * 64 + nf * 16 + (lane & 15)) * 64 +
                                            ks * 32 + (lane >> 4) * 8));
#pragma unroll
      for (int mf = 0; mf < 4; ++mf)
#pragma unroll
        for (int nf = 0; nf < 4; ++nf)
          acc[mf][nf] =
              __builtin_amdgcn_mfma_f32_16x16x32_bf16(af[mf], bfr[nf], acc[mf][nf], 0, 0, 0);
    }
    __syncthreads();
  }
}

// --------------- QKV GEMM: scatter to Q(scaled)/K (bh,s,64), Vt (bh,64,s) --
__global__ __launch_bounds__(256) void qkv_gemm_kernel(
    const unsigned short* __restrict__ xn, const unsigned short* __restrict__ wT,
    const float* __restrict__ bq, unsigned short* __restrict__ Qb,
    unsigned short* __restrict__ Kb, unsigned short* __restrict__ Vt) {
  __shared__ short lds_a[128 * 64];
  __shared__ short lds_b[128 * 64];
  const int b = blockIdx.z;
  const int m0 = blockIdx.x * 128, n0 = blockIdx.y * 128;
  f32x4 acc[4][4];
  gemm128_core(xn + (size_t)b * S_LEN * C_DIM, wT, C_DIM, m0, n0, lds_a, lds_b, acc);
  const int lane = threadIdx.x & 63, wid = threadIdx.x >> 6;
  const int wr = wid >> 1, wc = wid & 1;
#pragma unroll
  for (int mf = 0; mf < 4; ++mf) {
#pragma unroll
    for (int nf = 0; nf < 4; ++nf) {
      const int n = n0 + wc * 64 + nf * 16 + (lane & 15);
      const int part = n >> 9;
      const int h = (n >> 6) & 7;
      const int d = n & 63;
      const float bias = bq[n];
      const int m = m0 + wr * 64 + mf * 16 + (lane >> 4) * 4;
      if (part == 2) {
        u16x4 pk;
#pragma unroll
        for (int r = 0; r < 4; ++r) pk[r] = bf16u(acc[mf][nf][r] + bias);
        *(u16x4*)(Vt + ((size_t)(b * NH + h) * HD + d) * S_LEN + m) = pk;
      } else {
        unsigned short* dst = part == 0 ? Qb : Kb;
        const float sc = part == 0 ? 0.18033688011112042f : 1.0f;  // 0.125*log2(e)
#pragma unroll
        for (int r = 0; r < 4; ++r)
          dst[((size_t)(b * NH + h) * S_LEN + m + r) * HD + d] =
              bf16u((acc[mf][nf][r] + bias) * sc);
      }
    }
  }
}

// ----------------------------- flash attention -----------------------------
// 3 waves x 32 q-rows = 96 q/block. Swapped QK^T (S^T lane-local in q),
// in-register softmax, cvt_pk+permlane32_swap P redistribution, swapped PV
// (O^T), XOR-swizzled K/Vt LDS tiles, dbuf + counted vmcnt.
#define QBLK 96
__global__ __launch_bounds__(192) void attn_kernel(const unsigned short* __restrict__ Q,
                                                   const unsigned short* __restrict__ K,
                                                   const unsigned short* __restrict__ Vt,
                                                   unsigned short* __restrict__ O) {
  __shared__ __align__(16) char smem[45056];  // Q 12288 | kv0 16384 | kv1 16384
  const int tid = threadIdx.x;
  const int w = tid >> 6, l = tid & 63;
  const int l31 = l & 31, hi = l >> 5;
  const int bh = blockIdx.y, b = bh >> 3, h = bh & 7;
  const int q0 = blockIdx.x * QBLK;

  const char* gQ = (const char*)Q + (size_t)bh * S_LEN * 128;
  const char* gK = (const char*)K + (size_t)bh * S_LEN * 128;
  const char* gV = (const char*)Vt + (size_t)bh * HD * (S_LEN * 2);

  // per-thread KV staging descriptors (chunks 0..511 K, 512..1023 Vt)
  const char* kvp[6];
  unsigned kvadv[6];
  bool kvok[6];
#pragma unroll
  for (int i = 0; i < 6; ++i) {
    const int c = i * 192 + tid;
    kvok[i] = (c < 1024);
    if (c < 512) {
      const int r = c >> 3, ch = c & 7;
      kvp[i] = gK + (size_t)r * 128 + ((ch ^ (r & 7)) << 4);
      kvadv[i] = 64 * 128;  // next 64 K-rows
    } else {
      const int c2 = c & 511;
      const int dd = c2 >> 3, ch = c2 & 7;
      kvp[i] = gV + (size_t)dd * (S_LEN * 2) + ((ch ^ (dd & 7)) << 4);
      kvadv[i] = 128;  // next 64 k-cols within Vt row
    }
  }

  auto stage_kv = [&](char* nreg) {
#pragma unroll
    for (int i = 0; i < 6; ++i) {
      if (kvok[i]) {
        load_lds16((const void*)kvp[i], nreg + (i * 192 + w * 64) * 16);
        kvp[i] += kvadv[i];
      }
    }
  };

  // prologue: stage Q (768 chunks) then KV tile 0
#pragma unroll
  for (int i = 0; i < 4; ++i) {
    const int c0 = i * 192 + w * 64;
    const int c = c0 + l;
    const int r = c >> 3, ch = c & 7;
    load_lds16((const void*)(gQ + (size_t)(q0 + r) * 128 + ((ch ^ (r & 7)) << 4)),
               smem + c0 * 16);
  }
  stage_kv(smem + 12288);
  if (w == 0) asm volatile("s_waitcnt vmcnt(6)" ::: "memory");
  else        asm volatile("s_waitcnt vmcnt(5)" ::: "memory");
  __builtin_amdgcn_s_barrier();

  // hoist Q fragments (B-operand: lane holds Q[q=l31][d=(hi)*8+j + 16*d4])
  bf16x8 qf[4];
  {
    const int qrow = w * 32 + l31;
    const int qsw = qrow & 7;
#pragma unroll
    for (int d4 = 0; d4 < 4; ++d4)
      qf[d4] = *(const bf16x8*)(smem + qrow * 128 + (((d4 * 2 + hi) ^ qsw) << 4));
  }

  float m_run = -1e30f, lsum = 0.f;
  f32x16 oac0, oac1;
#pragma unroll
  for (int i = 0; i < 16; ++i) { oac0[i] = 0.f; oac1[i] = 0.f; }

  for (int kt = 0; kt < 36; ++kt) {
    char* region = smem + 12288 + ((kt & 1) << 14);
    if (kt < 35) {
      stage_kv(smem + 12288 + (((kt + 1) & 1) << 14));
      if (w == 0) asm volatile("s_waitcnt vmcnt(6)" ::: "memory");
      else        asm volatile("s_waitcnt vmcnt(5)" ::: "memory");
    } else {
      asm volatile("s_waitcnt vmcnt(0)" ::: "memory");
    }
    __builtin_amdgcn_s_barrier();

    const char* kreg = region;
    const char* vreg = region + 8192;
#pragma unroll
    for (int sub = 0; sub < 2; ++sub) {
      // ---- S^T = K · Q^T  (lane: col q=l31, rows k via C/D map) ----
      f32x16 st;
#pragma unroll
      for (int i = 0; i < 16; ++i) st[i] = 0.f;
      const int krow = sub * 32 + l31;
      const int ksw = krow & 7;
#pragma unroll
      for (int d4 = 0; d4 < 4; ++d4) {
        bf16x8 kf = *(const bf16x8*)(kreg + krow * 128 + (((d4 * 2 + hi) ^ ksw) << 4));
        st = __builtin_amdgcn_mfma_f32_32x32x16_bf16(kf, qf[d4], st, 0, 0, 0);
      }
      // ---- online softmax (log2 domain; scale folded into Q) ----
      float t8[8];
#pragma unroll
      for (int i = 0; i < 8; ++i) t8[i] = fmaxf(st[2 * i], st[2 * i + 1]);
#pragma unroll
      for (int i = 0; i < 4; ++i) t8[i] = fmaxf(t8[i], t8[i + 4]);
      float mt = fmaxf(fmaxf(t8[0], t8[1]), fmaxf(t8[2], t8[3]));
      float mo = mt;
      asm volatile("v_permlane32_swap_b32 %0, %1" : "+v"(mt), "+v"(mo));
      mt = fmaxf(mt, mo);
      const float mnew = fmaxf(m_run, mt);
      if (__any((mt - m_run) > 8.f)) {  // defer-max THR=8 (log2)
        const float corr = exp2f(m_run - mnew);
#pragma unroll
        for (int i = 0; i < 16; ++i) { oac0[i] *= corr; oac1[i] *= corr; }
        lsum *= corr;
        m_run = mnew;
      }
      float p[16];
#pragma unroll
      for (int i = 0; i < 16; ++i) p[i] = exp2f(st[i] - m_run);
      float a8[8];
#pragma unroll
      for (int i = 0; i < 8; ++i) a8[i] = p[2 * i] + p[2 * i + 1];
#pragma unroll
      for (int i = 0; i < 4; ++i) a8[i] += a8[i + 4];
      float rs = (a8[0] + a8[1]) + (a8[2] + a8[3]);
      float rsc = rs;
      asm volatile("v_permlane32_swap_b32 %0, %1" : "+v"(rs), "+v"(rsc));
      lsum += rs + rsc;
      // ---- P -> bf16 B-fragments via cvt_pk + permlane32_swap ----
      unsigned int wv[8];
#pragma unroll
      for (int j = 0; j < 8; ++j)
        asm("v_cvt_pk_bf16_f32 %0, %1, %2" : "=v"(wv[j]) : "v"(p[2 * j]), "v"(p[2 * j + 1]));
      asm volatile("v_permlane32_swap_b32 %0, %1" : "+v"(wv[0]), "+v"(wv[2]));
      asm volatile("v_permlane32_swap_b32 %0, %1" : "+v"(wv[1]), "+v"(wv[3]));
      asm volatile("v_permlane32_swap_b32 %0, %1" : "+v"(wv[4]), "+v"(wv[6]));
      asm volatile("v_permlane32_swap_b32 %0, %1" : "+v"(wv[5]), "+v"(wv[7]));
      typedef __attribute__((ext_vector_type(4))) unsigned int u32x4;
      u32x4 pw0 = {wv[0], wv[1], wv[2], wv[3]};
      u32x4 pw1 = {wv[4], wv[5], wv[6], wv[7]};
      bf16x8 pf0 = __builtin_bit_cast(bf16x8, pw0);
      bf16x8 pf1 = __builtin_bit_cast(bf16x8, pw1);
      // ---- O^T += V^T · P^T ----
      {
        const int vrow = l31;  // db=0: d=0..31
        const int vsw = vrow & 7;
        bf16x8 vf0 = *(const bf16x8*)(vreg + vrow * 128 + (((sub * 4 + 0 + hi) ^ vsw) << 4));
        oac0 = __builtin_amdgcn_mfma_f32_32x32x16_bf16(vf0, pf0, oac0, 0, 0, 0);
        bf16x8 vf1 = *(const bf16x8*)(vreg + vrow * 128 + (((sub * 4 + 2 + hi) ^ vsw) << 4));
        oac0 = __builtin_amdgcn_mfma_f32_32x32x16_bf16(vf1, pf1, oac0, 0, 0, 0);
      }
      {
        const int vrow = 32 + l31;  // db=1: d=32..63
        const int vsw = vrow & 7;
        bf16x8 vf0 = *(const bf16x8*)(vreg + vrow * 128 + (((sub * 4 + 0 + hi) ^ vsw) << 4));
        oac1 = __builtin_amdgcn_mfma_f32_32x32x16_bf16(vf0, pf0, oac1, 0, 0, 0);
        bf16x8 vf1 = *(const bf16x8*)(vreg + vrow * 128 + (((sub * 4 + 2 + hi) ^ vsw) << 4));
        oac1 = __builtin_amdgcn_mfma_f32_32x32x16_bf16(vf1, pf1, oac1, 0, 0, 0);
      }
    }
    __builtin_amdgcn_s_barrier();
  }

  // ---- normalize, transpose via LDS, coalesced store to ao (s, c) ----
  __syncthreads();
  const float inv = 1.f / lsum;
  unsigned short* ob = (unsigned short*)smem;  // [96][72]
  const int qrow = w * 32 + l31;
#pragma unroll
  for (int g = 0; g < 4; ++g) {
    u16x4 pk;
#pragma unroll
    for (int r = 0; r < 4; ++r) pk[r] = bf16u(oac0[g * 4 + r] * inv);
    *(u16x4*)(ob + qrow * 72 + (g * 8 + hi * 4)) = pk;
  }
#pragma unroll
  for (int g = 0; g < 4; ++g) {
    u16x4 pk;
#pragma unroll
    for (int r = 0; r < 4; ++r) pk[r] = bf16u(oac1[g * 4 + r] * inv);
    *(u16x4*)(ob + qrow * 72 + (32 + g * 8 + hi * 4)) = pk;
  }
  __syncthreads();
#pragma unroll
  for (int i = 0; i < 4; ++i) {
    const int c = i * 192 + tid;
    const int row = c >> 3, c8 = (c & 7) * 8;
    u16x8 v = *(const u16x8*)(ob + row * 72 + c8);
    *(u16x8*)(O + ((size_t)b * S_LEN + q0 + row) * C_DIM + h * HD + c8) = v;
  }
}

// ------------- proj GEMM (M=c_out, N=s) + bias + residual, fp32 out --------
__global__ __launch_bounds__(256) void proj_gemm_kernel(
    const unsigned short* __restrict__ wT, const unsigned short* __restrict__ ao,
    const float* __restrict__ bp, const float* __restrict__ x, float* __restrict__ out) {
  __shared__ short lds_a[128 * 64];
  __shared__ short lds_b[128 * 64];
  const int b = blockIdx.z;
  const int m0 = blockIdx.x * 128, n0 = blockIdx.y * 128;
  f32x4 acc[4][4];
  gemm128_core(wT, ao + (size_t)b * S_LEN * C_DIM, C_DIM, m0, n0, lds_a, lds_b, acc);
  const int lane = threadIdx.x & 63, wid = threadIdx.x >> 6;
  const int wr = wid >> 1, wc = wid & 1;
#pragma unroll
  for (int mf = 0; mf < 4; ++mf) {
#pragma unroll
    for (int nf = 0; nf < 4; ++nf) {
      const int n = n0 + wc * 64 + nf * 16 + (lane & 15);
#pragma unroll
      for (int r = 0; r < 4; ++r) {
        const int m = m0 + wr * 64 + mf * 16 + (lane >> 4) * 4 + r;
        const size_t idx = ((size_t)b * C_DIM + m) * S_LEN + n;
        out[idx] = x[idx] + acc[mf][nf][r] + bp[m];
      }
    }
  }
}

extern "C" void kernel_launch(void* const* d_in, const int* in_sizes, int n_in,
                              void* d_out, int out_size, void* d_ws, size_t ws_size,
                              hipStream_t stream) {
  const float* x = (const float*)d_in[0];
  const float* gamma = (const float*)d_in[1];
  const float* beta = (const float*)d_in[2];
  const float* w_qkv = (const float*)d_in[3];
  const float* b_qkv = (const float*)d_in[4];
  const float* w_proj = (const float*)d_in[5];
  const float* b_proj = (const float*)d_in[6];
  float* out = (float*)d_out;

  char* ws = (char*)d_ws;
  float* stats = (float*)ws;                                   // 1 KB
  unsigned short* xn = (unsigned short*)(ws + 1024);           // 9437184 B
  unsigned short* wqkvT = (unsigned short*)(ws + 9438208);     // 1572864 B
  unsigned short* wprojT = (unsigned short*)(ws + 11011072);   // 524288 B
  unsigned short* Qb = (unsigned short*)(ws + 11535360);       // 9437184 B
  unsigned short* Kb = (unsigned short*)(ws + 20972544);       // 9437184 B
  unsigned short* Vt = (unsigned short*)(ws + 30409728);       // 9437184 B
  unsigned short* ao = (unsigned short*)(ws + 39846912);       // 9437184 B

  hipLaunchKernelGGL(gn_stats_kernel, dim3(128), dim3(256), 0, stream, x, stats);
  hipLaunchKernelGGL(wt_kernel, dim3(24, 8), dim3(256), 0, stream, w_qkv, wqkvT, 3 * C_DIM, C_DIM);
  hipLaunchKernelGGL(wt_kernel, dim3(8, 8), dim3(256), 0, stream, w_proj, wprojT, C_DIM, C_DIM);
  hipLaunchKernelGGL(gn_norm_t_kernel, dim3(36, 8, 4), dim3(256), 0, stream, x, gamma, beta, stats, xn);
  hipLaunchKernelGGL(qkv_gemm_kernel, dim3(18, 12, 4), dim3(256), 0, stream, xn, wqkvT, b_qkv, Qb, Kb, Vt);
  hipLaunchKernelGGL(attn_kernel, dim3(24, 32), dim3(192), 0, stream, Qb, Kb, Vt, ao);
  hipLaunchKernelGGL(proj_gemm_kernel, dim3(4, 18, 4), dim3(256), 0, stream, wprojT, ao, b_proj, x, out);
}